// Round 1
// baseline (22800.450 us; speedup 1.0000x reference)
//
#include <hip/hip_runtime.h>
#include <math.h>

#define Bq   16
#define Tq   1024
#define INq  64
#define OUTq 64
#define Hq   512
#define Nq   128
#define Mq   40
#define KD   616      // 64 x + 40 r + 512 h
#define SP   644      // padded inp row stride (floats)
#define NWGATE 64
#define NWMEM  16
#define NWOUT  8
#define NWG    88
#define NT     512
#define EPSq 1e-8f

__device__ __forceinline__ float sigmf(float x){ return 1.f/(1.f + expf(-x)); }
__device__ __forceinline__ float softplusf(float x){ return (x > 20.f) ? x : log1pf(expf(x)); }

__device__ __forceinline__ void grid_barrier(unsigned* bar){
  __syncthreads();
  if (threadIdx.x == 0){
    __threadfence();  // release: flush this XCD's L2 (agent fence)
    unsigned g = __hip_atomic_load(bar + 32, __ATOMIC_RELAXED, __HIP_MEMORY_SCOPE_AGENT);
    unsigned arrived = __hip_atomic_fetch_add(bar, 1u, __ATOMIC_ACQ_REL, __HIP_MEMORY_SCOPE_AGENT);
    if (arrived == NWG - 1){
      __hip_atomic_store(bar, 0u, __ATOMIC_RELAXED, __HIP_MEMORY_SCOPE_AGENT);
      __hip_atomic_store(bar + 32, g + 1u, __ATOMIC_RELEASE, __HIP_MEMORY_SCOPE_AGENT);
    } else {
      while (__hip_atomic_load(bar + 32, __ATOMIC_ACQUIRE, __HIP_MEMORY_SCOPE_AGENT) == g){
        __builtin_amdgcn_s_sleep(1);
      }
    }
    __threadfence();  // acquire: invalidate L1/L2 before reading peers' data
  }
  __syncthreads();
}

extern "C" __global__ void __launch_bounds__(NT, 2)
ntm_kernel(const float* __restrict__ xg,  const float* __restrict__ h0g,
           const float* __restrict__ c0g, const float* __restrict__ mem0g,
           const float* __restrict__ read0g,
           const float* __restrict__ Wih, const float* __restrict__ bih,
           const float* __restrict__ Whh, const float* __restrict__ bhh,
           const float* __restrict__ Wfc, const float* __restrict__ bfc,
           const float* __restrict__ We,  const float* __restrict__ be,
           const float* __restrict__ Wa,  const float* __restrict__ ba,
           const float* __restrict__ Wk,  const float* __restrict__ bk,
           const float* __restrict__ Wb,  const float* __restrict__ bbeta,
           float* __restrict__ yout, unsigned* __restrict__ bar,
           float* __restrict__ r_cur, float* __restrict__ h_buf)
{
  const int wg  = blockIdx.x;
  const int tid = threadIdx.x;
  __shared__ __align__(16) char smem[62464];

  if (wg < NWGATE){
    // ---------------- gate workgroup: owns h-indices [wg*8, wg*8+8) ----------------
    float* inp_s  = (float*)smem;               // 16 x 644 floats
    float* red_s  = (float*)(smem + 41216);     // 32*16*9
    float* gate_s = (float*)(smem + 59648);     // 32*16
    float* c_s    = (float*)(smem + 61696);     // 8*16
    float* bias_s = (float*)(smem + 62208);     // 32

    const int o2   = tid & 15;
    const int bg   = (tid >> 4) & 3;
    const int kseg = tid >> 6;

    // persistent gate weights in registers: 2 rows x 80 k = 40 float4
    float4 w4[2][20];
    #pragma unroll
    for (int j = 0; j < 2; ++j){
      const int l   = o2 + 16*j;
      const int row = (l >> 3)*Hq + wg*8 + (l & 7);
      const float* wihr = Wih + row*104;
      const float* whhr = Whh + row*512;
      #pragma unroll
      for (int kk = 0; kk < 20; ++kk){
        float v[4];
        #pragma unroll
        for (int c4 = 0; c4 < 4; ++c4){
          const int k = kseg*80 + kk*4 + c4;
          v[c4] = (k < 104) ? wihr[k] : ((k < KD) ? whhr[k - 104] : 0.f);
        }
        w4[j][kk] = make_float4(v[0], v[1], v[2], v[3]);
      }
    }
    if (tid < 32){
      const int row = (tid >> 3)*Hq + wg*8 + (tid & 7);
      bias_s[tid] = bih[row] + bhh[row];
    }
    if (tid < 128){
      const int hh = tid & 7, b = tid >> 3;
      c_s[hh*16 + b] = c0g[b*Hq + wg*8 + hh];
    }
    if (tid < 448){                    // zero pad cols 616..643
      const int b = tid / 28, q = tid - b*28;
      inp_s[b*SP + KD + q] = 0.f;
    }
    { // stage x(0) and h0
      const float4* x4 = (const float4*)xg;
      if (tid < 256){ const int b = tid >> 4, q = tid & 15;
        *(float4*)&inp_s[b*SP + q*4] = x4[(b*Tq + 0)*16 + q]; }
      const float4* h4 = (const float4*)h0g;
      #pragma unroll
      for (int j = 0; j < 4; ++j){ const int i4 = tid + 512*j;
        const int b = i4 >> 7, q = i4 & 127;
        *(float4*)&inp_s[b*SP + 104 + q*4] = h4[b*128 + q]; }
    }

    for (int t = 0; t < Tq; ++t){
      // stage r(t-1)
      const float4* r4 = (const float4*)((t == 0) ? read0g : r_cur);
      if (tid < 160){ const int b = tid / 10, q = tid - b*10;
        *(float4*)&inp_s[b*SP + 64 + q*4] = r4[b*10 + q]; }
      __syncthreads();

      float acc[2][4] = {};
      const int kb = kseg*80;
      #pragma unroll
      for (int kk = 0; kk < 20; ++kk){
        #pragma unroll
        for (int bl = 0; bl < 4; ++bl){
          const int b = 4*bg + bl;
          const float4 f = *(const float4*)&inp_s[b*SP + kb + kk*4];
          #pragma unroll
          for (int j = 0; j < 2; ++j){
            acc[j][bl] += w4[j][kk].x*f.x + w4[j][kk].y*f.y
                        + w4[j][kk].z*f.z + w4[j][kk].w*f.w;
          }
        }
      }
      #pragma unroll
      for (int j = 0; j < 2; ++j){
        #pragma unroll
        for (int bl = 0; bl < 4; ++bl){
          red_s[((o2 + 16*j)*16 + 4*bg + bl)*9 + kseg] = acc[j][bl];
        }
      }
      __syncthreads();
      { const int l = tid >> 4, b = tid & 15;
        const float* rp = &red_s[(l*16 + b)*9];
        gate_s[l*16 + b] = rp[0]+rp[1]+rp[2]+rp[3]+rp[4]+rp[5]+rp[6]+rp[7] + bias_s[l]; }
      __syncthreads();
      if (tid < 128){
        const int hh = tid & 7, b = tid >> 3;
        const float gi = gate_s[(0*8 + hh)*16 + b];
        const float gf = gate_s[(1*8 + hh)*16 + b];
        const float gc = gate_s[(2*8 + hh)*16 + b];
        const float go = gate_s[(3*8 + hh)*16 + b];
        const float iv = sigmf(gi), fv = sigmf(gf), gv = tanhf(gc), ov = sigmf(go);
        const float cn = fv*c_s[hh*16 + b] + iv*gv;
        const float hn = ov*tanhf(cn);
        c_s[hh*16 + b] = cn;
        h_buf[(t & 1)*(Bq*Hq) + b*Hq + wg*8 + hh] = hn;
        if (t == Tq - 1){
          yout[Bq*Tq*OUTq + b*Hq + wg*8 + hh] = hn;                 // final h
          yout[Bq*Tq*OUTq + Bq*Hq + b*Hq + wg*8 + hh] = cn;         // final c
        }
      }
      grid_barrier(bar);                    // A: h(t) visible
      if (t + 1 < Tq){                      // prefetch h(t), x(t+1) off critical path
        const float4* h4 = (const float4*)(h_buf + (t & 1)*(Bq*Hq));
        #pragma unroll
        for (int j = 0; j < 4; ++j){ const int i4 = tid + 512*j;
          const int b = i4 >> 7, q = i4 & 127;
          *(float4*)&inp_s[b*SP + 104 + q*4] = h4[b*128 + q]; }
        const float4* x4 = (const float4*)xg;
        if (tid < 256){ const int b = tid >> 4, q = tid & 15;
          *(float4*)&inp_s[b*SP + q*4] = x4[(b*Tq + (t + 1))*16 + q]; }
      }
      grid_barrier(bar);                    // B: r(t) visible
    }
  }
  else if (wg < NWGATE + NWMEM){
    // ---------------- memory workgroup: owns batch b ----------------
    const int bat = wg - NWGATE;
    float* mem_s  = (float*)smem;               // 128 x 41
    float* h_s    = (float*)(smem + 20992);     // 512
    float* key_s  = (float*)(smem + 23040);     // 40
    float* e_s    = (float*)(smem + 23200);     // 40
    float* a_s    = (float*)(smem + 23360);     // 40
    float* hred_s = (float*)(smem + 23520);     // 128*4
    float* w_s    = (float*)(smem + 25568);     // 128
    float* sc_s   = (float*)(smem + 26080);     // 128
    float* rred_s = (float*)(smem + 26592);     // 40*8
    float* scal_s = (float*)(smem + 27872);     // 8

    #pragma unroll
    for (int j = 0; j < 10; ++j){
      const int e = j*512 + tid;
      const int n = e / 40, m = e - n*40;
      mem_s[n*41 + m] = mem0g[bat*(Nq*Mq) + e];
    }
    const int o  = tid & 127;
    const int kc = tid >> 7;
    const float* wrow = nullptr; float hbias = 0.f;
    if      (o < 40){  wrow = Wk + o*Hq;        hbias = bk[o]; }
    else if (o < 80){  wrow = We + (o-40)*Hq;   hbias = be[o-40]; }
    else if (o < 120){ wrow = Wa + (o-80)*Hq;   hbias = ba[o-80]; }
    else if (o == 120){ wrow = Wb;              hbias = bbeta[0]; }
    float4 wv[32];
    if (wrow){
      const float4* wp = (const float4*)(wrow + kc*128);
      #pragma unroll
      for (int kk = 0; kk < 32; ++kk) wv[kk] = wp[kk];
    } else {
      #pragma unroll
      for (int kk = 0; kk < 32; ++kk) wv[kk] = make_float4(0.f,0.f,0.f,0.f);
    }

    for (int t = 0; t < Tq; ++t){
      grid_barrier(bar);                    // A: h(t) ready
      h_s[tid] = h_buf[(t & 1)*(Bq*Hq) + bat*Hq + tid];
      __syncthreads();
      { // heads GEMV: 121 outputs x 512
        float p = 0.f;
        #pragma unroll
        for (int kk = 0; kk < 32; ++kk){
          const float4 hv = *(const float4*)&h_s[kc*128 + kk*4];
          p += wv[kk].x*hv.x + wv[kk].y*hv.y + wv[kk].z*hv.z + wv[kk].w*hv.w;
        }
        hred_s[o*4 + kc] = p;
      }
      __syncthreads();
      if (tid < 128){
        const float s = hred_s[tid*4] + hred_s[tid*4+1] + hred_s[tid*4+2] + hred_s[tid*4+3] + hbias;
        if      (tid < 40)  key_s[tid]     = tanhf(s);
        else if (tid < 80)  e_s[tid-40]    = sigmf(s);
        else if (tid < 120) a_s[tid-80]    = tanhf(s);
        else if (tid == 120) scal_s[1]     = softplusf(s) + EPSq;  // beta
      }
      __syncthreads();
      if (tid < 64){
        float v = (tid < 40) ? key_s[tid]*key_s[tid] : 0.f;
        #pragma unroll
        for (int off = 32; off; off >>= 1) v += __shfl_xor(v, off);
        if (tid == 0) scal_s[0] = 1.f/(sqrtf(v) + EPSq);           // 1/(||key||+eps)
      }
      __syncthreads();
      if (tid < 128){
        const int n = tid;
        float q = 0.f, d = 0.f;
        #pragma unroll
        for (int m = 0; m < 40; ++m){
          const float mv = mem_s[n*41 + m];
          q += mv*mv; d += mv*key_s[m];
        }
        const float sim = d * scal_s[0] / (sqrtf(q) + EPSq);
        sc_s[n] = scal_s[1] * sim;
      }
      __syncthreads();
      if (tid < 64){
        float v = fmaxf(sc_s[tid], sc_s[tid + 64]);
        #pragma unroll
        for (int off = 32; off; off >>= 1) v = fmaxf(v, __shfl_xor(v, off));
        if (tid == 0) scal_s[2] = v;
      }
      __syncthreads();
      if (tid < 128) w_s[tid] = expf(sc_s[tid] - scal_s[2]);
      __syncthreads();
      if (tid < 64){
        float v = w_s[tid] + w_s[tid + 64];
        #pragma unroll
        for (int off = 32; off; off >>= 1) v += __shfl_xor(v, off);
        if (tid == 0) scal_s[3] = 1.f/v;
      }
      __syncthreads();
      if (tid < 128) w_s[tid] *= scal_s[3];
      __syncthreads();
      { // erase/add write
        const int n = tid & 127, mg = tid >> 7;
        const float wn = w_s[n];
        #pragma unroll
        for (int mm = 0; mm < 10; ++mm){
          const int m = mg*10 + mm, idx = n*41 + m;
          const float mv = mem_s[idx];
          mem_s[idx] = mv*(1.f - wn*e_s[m]) + wn*a_s[m];
        }
      }
      __syncthreads();
      if (tid < 320){ // read vector partials
        const int m = tid % 40, ng = tid / 40;
        float p = 0.f;
        #pragma unroll
        for (int j = 0; j < 16; ++j){
          const int n = ng*16 + j;
          p += w_s[n]*mem_s[n*41 + m];
        }
        rred_s[m*8 + ng] = p;
      }
      __syncthreads();
      if (tid < 40){
        float rsum = 0.f;
        #pragma unroll
        for (int j = 0; j < 8; ++j) rsum += rred_s[tid*8 + j];
        r_cur[bat*Mq + tid] = rsum;
      }
      grid_barrier(bar);                    // B: r(t) visible
    }
  }
  else {
    // ---------------- out workgroup: owns 8 output columns ----------------
    const int oo = wg - (NWGATE + NWMEM);
    float* wfc_s  = (float*)smem;               // 8 x 516
    float* hall_s = (float*)(smem + 16512);     // 16 x 516
    float* ored_s = (float*)(smem + 49536);     // 128*4
    float* bfc_s  = (float*)(smem + 51584);     // 8
    {
      const float4* wp = (const float4*)Wfc;
      #pragma unroll
      for (int j = 0; j < 2; ++j){
        const int i4 = j*512 + tid;
        const int col = i4 >> 7, q = i4 & 127;
        *(float4*)&wfc_s[col*516 + q*4] = wp[(oo*8 + col)*128 + q];
      }
      if (tid < 8) bfc_s[tid] = bfc[oo*8 + tid];
    }
    for (int t = 0; t < Tq; ++t){
      grid_barrier(bar);                    // A
      grid_barrier(bar);                    // B
      // compute out(t) hidden behind next gate phase (h parity valid 1 extra step)
      const float4* h4 = (const float4*)(h_buf + (t & 1)*(Bq*Hq));
      #pragma unroll
      for (int j = 0; j < 4; ++j){ const int i4 = tid + 512*j;
        const int b = i4 >> 7, q = i4 & 127;
        *(float4*)&hall_s[b*516 + q*4] = h4[b*128 + q]; }
      __syncthreads();
      {
        const int col = tid & 7, b = (tid >> 3) & 15, kc = tid >> 7;
        float p = 0.f;
        #pragma unroll
        for (int kk = 0; kk < 32; ++kk){
          const int k = kc*128 + kk*4;
          const float4 wvv = *(const float4*)&wfc_s[col*516 + k];
          const float4 hvv = *(const float4*)&hall_s[b*516 + k];
          p += wvv.x*hvv.x + wvv.y*hvv.y + wvv.z*hvv.z + wvv.w*hvv.w;
        }
        ored_s[(b*8 + col)*4 + kc] = p;
      }
      __syncthreads();
      if (tid < 128){
        const int b = tid >> 3, col = tid & 7;
        const float* op = &ored_s[(b*8 + col)*4];
        const float s = op[0] + op[1] + op[2] + op[3] + bfc_s[col];
        yout[(b*Tq + t)*OUTq + oo*8 + col] = tanhf(s);
      }
      __syncthreads();
    }
  }
}

extern "C" void kernel_launch(void* const* d_in, const int* in_sizes, int n_in,
                              void* d_out, int out_size, void* d_ws, size_t ws_size,
                              hipStream_t stream){
  const float* xg    = (const float*)d_in[0];
  const float* h0g   = (const float*)d_in[1];
  const float* c0g   = (const float*)d_in[2];
  const float* mem0g = (const float*)d_in[3];
  const float* read0g= (const float*)d_in[4];
  const float* Wih   = (const float*)d_in[5];
  const float* bih   = (const float*)d_in[6];
  const float* Whh   = (const float*)d_in[7];
  const float* bhh   = (const float*)d_in[8];
  const float* Wfc   = (const float*)d_in[9];
  const float* bfc   = (const float*)d_in[10];
  const float* We    = (const float*)d_in[11];
  const float* be    = (const float*)d_in[12];
  const float* Wa    = (const float*)d_in[13];
  const float* ba    = (const float*)d_in[14];
  const float* Wk    = (const float*)d_in[15];
  const float* bk    = (const float*)d_in[16];
  const float* Wb    = (const float*)d_in[17];
  const float* bbeta = (const float*)d_in[18];

  float*    yout  = (float*)d_out;
  unsigned* bar   = (unsigned*)d_ws;
  float*    r_cur = (float*)((char*)d_ws + 256);
  float*    h_buf = (float*)((char*)d_ws + 4096);

  hipMemsetAsync(d_ws, 0, 256, stream);   // barrier count/gen = 0 every launch
  hipLaunchKernelGGL(ntm_kernel, dim3(NWG), dim3(NT), 0, stream,
                     xg, h0g, c0g, mem0g, read0g, Wih, bih, Whh, bhh,
                     Wfc, bfc, We, be, Wa, ba, Wk, bk, Wb, bbeta,
                     yout, bar, r_cur, h_buf);
}

// Round 2
// 18003.430 us; speedup vs baseline: 1.2665x; 1.2665x over previous
//
#include <hip/hip_runtime.h>
#include <math.h>

#define Bq   16
#define Tq   1024
#define INq  64
#define OUTq 64
#define Hq   512
#define Nq   128
#define Mq   40
#define SP   580      // inp row stride (floats): x[0,64) h[64,576), stride%8=4 -> <=2-way banks
#define NWGATE 128
#define NWMEM  16
#define NWOUT  8
#define NWG    152
#define NT     512
#define EPSq 1e-8f

__device__ __forceinline__ float sigmf(float x){ return 1.f/(1.f + expf(-x)); }
__device__ __forceinline__ float softplusf(float x){ return (x > 20.f) ? x : log1pf(expf(x)); }

// Flag-array grid barrier: one flag word (own cache line) per WG, release store;
// 3 waves poll all flags (relaxed agent loads bypass stale L1/L2), one acquire
// fence (L2 inv) on exit. No same-line RMW -> no 152-way serialization.
__device__ __forceinline__ void gbar(unsigned* flags, unsigned target){
  __syncthreads();
  if (threadIdx.x == 0)
    __hip_atomic_store(&flags[blockIdx.x*16], target, __ATOMIC_RELEASE, __HIP_MEMORY_SCOPE_AGENT);
  if (threadIdx.x < 192){
    const int f = (threadIdx.x < NWG) ? (int)threadIdx.x : (NWG-1);
    while (__hip_atomic_load(&flags[f*16], __ATOMIC_RELAXED, __HIP_MEMORY_SCOPE_AGENT) < target) { }
    __builtin_amdgcn_fence(__ATOMIC_ACQUIRE, "agent");
  }
  __syncthreads();
}

extern "C" __global__ void __launch_bounds__(NT, 2)
ntm_kernel(const float* __restrict__ xg,  const float* __restrict__ h0g,
           const float* __restrict__ c0g, const float* __restrict__ mem0g,
           const float* __restrict__ read0g,
           const float* __restrict__ Wih, const float* __restrict__ bih,
           const float* __restrict__ Whh, const float* __restrict__ bhh,
           const float* __restrict__ Wfc, const float* __restrict__ bfc,
           const float* __restrict__ We,  const float* __restrict__ be,
           const float* __restrict__ Wa,  const float* __restrict__ ba,
           const float* __restrict__ Wk,  const float* __restrict__ bk,
           const float* __restrict__ Wb,  const float* __restrict__ bbeta,
           float* __restrict__ yout, unsigned* __restrict__ flags,
           float* __restrict__ r_cur, float* __restrict__ h_buf)
{
  const int wg  = blockIdx.x;
  const int tid = threadIdx.x;
  __shared__ __align__(16) char smem[52352];

  if (wg < NWGATE){
    // ------- gate WG: owns h-indices [wg*4, wg*4+4) => 16 gate rows -------
    float* inp_s  = (float*)smem;               // 16 x 580 floats (x | h)
    float* red_s  = (float*)(smem + 37120);     // [b*145 + l*9 + kseg], 2320 floats
    float* r_s    = (float*)(smem + 46400);     // 16 x 44
    float* gate_s = (float*)(smem + 49216);     // [b*16 + l], 256
    float* c_s    = (float*)(smem + 50240);     // [hh*16 + b], 64
    float* bias_s = (float*)(smem + 50496);     // 16

    const int l    = tid & 15;         // gate row within WG: g = l>>2, hh = l&3
    const int bg   = (tid >> 4) & 3;
    const int kseg = tid >> 6;         // = wave id (uniform per wave)
    const int row  = (l >> 2)*Hq + wg*4 + (l & 3);

    // persistent weights: main slice (x+h) 20 float4, r slice 10 float4
    float4 w4[20];
    #pragma unroll
    for (int kk = 0; kk < 20; ++kk){
      float v[4];
      #pragma unroll
      for (int c4 = 0; c4 < 4; ++c4){
        const int k = kseg*80 + kk*4 + c4;
        v[c4] = (k < 64) ? Wih[row*104 + k] : ((k < 576) ? Whh[row*512 + (k - 64)] : 0.f);
      }
      w4[kk] = make_float4(v[0], v[1], v[2], v[3]);
    }
    float4 wr[10];
    { const float* wir = Wih + row*104 + 64;
      #pragma unroll
      for (int q = 0; q < 10; ++q) wr[q] = *(const float4*)&wir[q*4]; }
    if (tid < 16) bias_s[tid] = bih[row] + bhh[row];
    if (tid < 64){ const int hh = tid & 3, b = tid >> 2;
      c_s[hh*16 + b] = c0g[b*Hq + wg*4 + hh]; }
    { // stage x(0), h(-1)=h0
      const float4* x4 = (const float4*)xg;
      if (tid < 256){ const int b = tid >> 4, q = tid & 15;
        *(float4*)&inp_s[b*SP + q*4] = x4[(b*Tq + 0)*16 + q]; }
      const float4* h4 = (const float4*)h0g;
      #pragma unroll
      for (int j = 0; j < 4; ++j){ const int i4 = tid + 512*j;
        const int b = i4 >> 7, q = i4 & 127;
        *(float4*)&inp_s[b*SP + 64 + q*4] = h4[b*128 + q]; }
    }
    __syncthreads();

    for (int t = 0; t < Tq; ++t){
      // ---- main GEMV (x+h part, k<576): overlaps the mem WGs' phase ----
      float acc[4] = {0.f, 0.f, 0.f, 0.f};
      const int kb = kseg*80;
      if (kseg < 7){
        #pragma unroll
        for (int kk = 0; kk < 20; ++kk){
          #pragma unroll
          for (int bl = 0; bl < 4; ++bl){
            const float4 f = *(const float4*)&inp_s[(4*bg + bl)*SP + kb + kk*4];
            acc[bl] += w4[kk].x*f.x + w4[kk].y*f.y + w4[kk].z*f.z + w4[kk].w*f.w;
          }
        }
      } else {
        #pragma unroll
        for (int kk = 0; kk < 4; ++kk){
          #pragma unroll
          for (int bl = 0; bl < 4; ++bl){
            const float4 f = *(const float4*)&inp_s[(4*bg + bl)*SP + kb + kk*4];
            acc[bl] += w4[kk].x*f.x + w4[kk].y*f.y + w4[kk].z*f.z + w4[kk].w*f.w;
          }
        }
      }
      #pragma unroll
      for (int bl = 0; bl < 4; ++bl)
        red_s[(4*bg + bl)*145 + l*9 + kseg] = acc[bl];

      if (t > 0) gbar(flags, 2u*t);          // barB(t-1): r(t-1) visible
      { // stage r(t-1)
        const float4* r4 = (const float4*)((t == 0) ? read0g : r_cur);
        if (tid < 160){ const int b = tid / 10, q = tid - b*10;
          *(float4*)&r_s[b*44 + q*4] = r4[b*10 + q]; }
      }
      __syncthreads();
      // ---- finalize: partial sums + bias + r-contribution ----
      if (tid < 256){
        const int fb = tid >> 4;             // fl == l
        float s = bias_s[l];
        const float* rp = &red_s[fb*145 + l*9];
        s += rp[0]+rp[1]+rp[2]+rp[3]+rp[4]+rp[5]+rp[6]+rp[7];
        #pragma unroll
        for (int q = 0; q < 10; ++q){
          const float4 rv = *(const float4*)&r_s[fb*44 + q*4];
          s += wr[q].x*rv.x + wr[q].y*rv.y + wr[q].z*rv.z + wr[q].w*rv.w;
        }
        gate_s[fb*16 + l] = s;
      }
      __syncthreads();
      if (tid < 64){
        const int hh = tid & 3, b = tid >> 2;
        const float gi = gate_s[b*16 + hh];
        const float gf = gate_s[b*16 + 4 + hh];
        const float gc = gate_s[b*16 + 8 + hh];
        const float go = gate_s[b*16 + 12 + hh];
        const float iv = sigmf(gi), fv = sigmf(gf), gv = tanhf(gc), ov = sigmf(go);
        const float cn = fv*c_s[hh*16 + b] + iv*gv;
        const float hn = ov*tanhf(cn);
        c_s[hh*16 + b] = cn;
        h_buf[(t & 1)*(Bq*Hq) + b*Hq + wg*4 + hh] = hn;
        if (t == Tq - 1){
          yout[Bq*Tq*OUTq + b*Hq + wg*4 + hh] = hn;                // final h
          yout[Bq*Tq*OUTq + Bq*Hq + b*Hq + wg*4 + hh] = cn;        // final c
        }
      }
      gbar(flags, 2u*t + 1u);                // barA(t): h(t) visible
      if (t + 1 < Tq){                       // prefetch h(t), x(t+1)
        const float4* h4 = (const float4*)(h_buf + (t & 1)*(Bq*Hq));
        #pragma unroll
        for (int j = 0; j < 4; ++j){ const int i4 = tid + 512*j;
          const int b = i4 >> 7, q = i4 & 127;
          *(float4*)&inp_s[b*SP + 64 + q*4] = h4[b*128 + q]; }
        const float4* x4 = (const float4*)xg;
        if (tid < 256){ const int b = tid >> 4, q = tid & 15;
          *(float4*)&inp_s[b*SP + q*4] = x4[(b*Tq + (t + 1))*16 + q]; }
      }
      __syncthreads();
    }
    // final arrive-only at barB(1023) so mem/out WGs can exit
    __syncthreads();
    if (tid == 0)
      __hip_atomic_store(&flags[wg*16], 2u*Tq, __ATOMIC_RELEASE, __HIP_MEMORY_SCOPE_AGENT);
  }
  else if (wg < NWGATE + NWMEM){
    // ---------------- memory workgroup: owns batch b ----------------
    const int bat = wg - NWGATE;
    float* mem_s  = (float*)smem;               // 128 x 41
    float* h_s    = (float*)(smem + 20992);     // 512
    float* key_s  = (float*)(smem + 23040);     // 40
    float* e_s    = (float*)(smem + 23200);     // 40
    float* a_s    = (float*)(smem + 23360);     // 40
    float* hred_s = (float*)(smem + 23520);     // 128*4
    float* w_s    = (float*)(smem + 25568);     // 128
    float* sc_s   = (float*)(smem + 26080);     // 128
    float* rred_s = (float*)(smem + 26592);     // 40*8
    float* scal_s = (float*)(smem + 27872);     // 8

    #pragma unroll
    for (int j = 0; j < 10; ++j){
      const int e = j*512 + tid;
      const int n = e / 40, m = e - n*40;
      mem_s[n*41 + m] = mem0g[bat*(Nq*Mq) + e];
    }
    const int o  = tid & 127;
    const int kc = tid >> 7;
    const float* wrow = nullptr; float hbias = 0.f;
    if      (o < 40){  wrow = Wk + o*Hq;        hbias = bk[o]; }
    else if (o < 80){  wrow = We + (o-40)*Hq;   hbias = be[o-40]; }
    else if (o < 120){ wrow = Wa + (o-80)*Hq;   hbias = ba[o-80]; }
    else if (o == 120){ wrow = Wb;              hbias = bbeta[0]; }
    float4 wv[32];
    if (wrow){
      const float4* wp = (const float4*)(wrow + kc*128);
      #pragma unroll
      for (int kk = 0; kk < 32; ++kk) wv[kk] = wp[kk];
    } else {
      #pragma unroll
      for (int kk = 0; kk < 32; ++kk) wv[kk] = make_float4(0.f,0.f,0.f,0.f);
    }

    for (int t = 0; t < Tq; ++t){
      gbar(flags, 2u*t + 1u);               // barA(t): h(t) ready
      h_s[tid] = h_buf[(t & 1)*(Bq*Hq) + bat*Hq + tid];
      __syncthreads();
      { // heads GEMV: 121 outputs x 512
        float p = 0.f;
        #pragma unroll
        for (int kk = 0; kk < 32; ++kk){
          const float4 hv = *(const float4*)&h_s[kc*128 + kk*4];
          p += wv[kk].x*hv.x + wv[kk].y*hv.y + wv[kk].z*hv.z + wv[kk].w*hv.w;
        }
        hred_s[o*4 + kc] = p;
      }
      __syncthreads();
      if (tid < 128){
        const float s = hred_s[tid*4] + hred_s[tid*4+1] + hred_s[tid*4+2] + hred_s[tid*4+3] + hbias;
        if      (tid < 40)  key_s[tid]     = tanhf(s);
        else if (tid < 80)  e_s[tid-40]    = sigmf(s);
        else if (tid < 120) a_s[tid-80]    = tanhf(s);
        else if (tid == 120) scal_s[1]     = softplusf(s) + EPSq;  // beta
      }
      __syncthreads();
      if (tid < 64){
        float v = (tid < 40) ? key_s[tid]*key_s[tid] : 0.f;
        #pragma unroll
        for (int off = 32; off; off >>= 1) v += __shfl_xor(v, off);
        if (tid == 0) scal_s[0] = 1.f/(sqrtf(v) + EPSq);           // 1/(||key||+eps)
      }
      __syncthreads();
      if (tid < 128){
        const int n = tid;
        float q = 0.f, d = 0.f;
        #pragma unroll
        for (int m = 0; m < 40; ++m){
          const float mv = mem_s[n*41 + m];
          q += mv*mv; d += mv*key_s[m];
        }
        const float sim = d * scal_s[0] / (sqrtf(q) + EPSq);
        sc_s[n] = scal_s[1] * sim;
      }
      __syncthreads();
      if (tid < 64){
        float v = fmaxf(sc_s[tid], sc_s[tid + 64]);
        #pragma unroll
        for (int off = 32; off; off >>= 1) v = fmaxf(v, __shfl_xor(v, off));
        if (tid == 0) scal_s[2] = v;
      }
      __syncthreads();
      if (tid < 128) w_s[tid] = expf(sc_s[tid] - scal_s[2]);
      __syncthreads();
      if (tid < 64){
        float v = w_s[tid] + w_s[tid + 64];
        #pragma unroll
        for (int off = 32; off; off >>= 1) v += __shfl_xor(v, off);
        if (tid == 0) scal_s[3] = 1.f/v;
      }
      __syncthreads();
      if (tid < 128) w_s[tid] *= scal_s[3];
      __syncthreads();
      { // erase/add write
        const int n = tid & 127, mg = tid >> 7;
        const float wn = w_s[n];
        #pragma unroll
        for (int mm = 0; mm < 10; ++mm){
          const int m = mg*10 + mm, idx = n*41 + m;
          const float mv = mem_s[idx];
          mem_s[idx] = mv*(1.f - wn*e_s[m]) + wn*a_s[m];
        }
      }
      __syncthreads();
      if (tid < 320){ // read vector partials
        const int m = tid % 40, ng = tid / 40;
        float p = 0.f;
        #pragma unroll
        for (int j = 0; j < 16; ++j){
          const int n = ng*16 + j;
          p += w_s[n]*mem_s[n*41 + m];
        }
        rred_s[m*8 + ng] = p;
      }
      __syncthreads();
      if (tid < 40){
        float rsum = 0.f;
        #pragma unroll
        for (int j = 0; j < 8; ++j) rsum += rred_s[tid*8 + j];
        r_cur[bat*Mq + tid] = rsum;
      }
      gbar(flags, 2u*t + 2u);               // barB(t): r(t) visible
    }
  }
  else {
    // ---------------- out workgroup: owns 8 output columns ----------------
    const int oo = wg - (NWGATE + NWMEM);
    float* wfc_s  = (float*)smem;               // 8 x 516
    float* hall_s = (float*)(smem + 16512);     // 16 x 516
    float* ored_s = (float*)(smem + 49536);     // 128*4
    float* bfc_s  = (float*)(smem + 51584);     // 8
    {
      const float4* wp = (const float4*)Wfc;
      #pragma unroll
      for (int j = 0; j < 2; ++j){
        const int i4 = j*512 + tid;
        const int col = i4 >> 7, q = i4 & 127;
        *(float4*)&wfc_s[col*516 + q*4] = wp[(oo*8 + col)*128 + q];
      }
      if (tid < 8) bfc_s[tid] = bfc[oo*8 + tid];
    }
    for (int t = 0; t < Tq; ++t){
      gbar(flags, 2u*t + 1u);               // A
      gbar(flags, 2u*t + 2u);               // B
      // compute out(t) hidden behind next gate/mem phase (h parity valid 1 extra step)
      const float4* h4 = (const float4*)(h_buf + (t & 1)*(Bq*Hq));
      #pragma unroll
      for (int j = 0; j < 4; ++j){ const int i4 = tid + 512*j;
        const int b = i4 >> 7, q = i4 & 127;
        *(float4*)&hall_s[b*516 + q*4] = h4[b*128 + q]; }
      __syncthreads();
      {
        const int col = tid & 7, b = (tid >> 3) & 15, kc = tid >> 7;
        float p = 0.f;
        #pragma unroll
        for (int kk = 0; kk < 32; ++kk){
          const int k = kc*128 + kk*4;
          const float4 wvv = *(const float4*)&wfc_s[col*516 + k];
          const float4 hvv = *(const float4*)&hall_s[b*516 + k];
          p += wvv.x*hvv.x + wvv.y*hvv.y + wvv.z*hvv.z + wvv.w*hvv.w;
        }
        ored_s[(b*8 + col)*4 + kc] = p;
      }
      __syncthreads();
      if (tid < 128){
        const int b = tid >> 3, col = tid & 7;
        const float* op = &ored_s[(b*8 + col)*4];
        const float s = op[0] + op[1] + op[2] + op[3] + bfc_s[col];
        yout[(b*Tq + t)*OUTq + oo*8 + col] = tanhf(s);
      }
      __syncthreads();
    }
  }
}

extern "C" void kernel_launch(void* const* d_in, const int* in_sizes, int n_in,
                              void* d_out, int out_size, void* d_ws, size_t ws_size,
                              hipStream_t stream){
  const float* xg    = (const float*)d_in[0];
  const float* h0g   = (const float*)d_in[1];
  const float* c0g   = (const float*)d_in[2];
  const float* mem0g = (const float*)d_in[3];
  const float* read0g= (const float*)d_in[4];
  const float* Wih   = (const float*)d_in[5];
  const float* bih   = (const float*)d_in[6];
  const float* Whh   = (const float*)d_in[7];
  const float* bhh   = (const float*)d_in[8];
  const float* Wfc   = (const float*)d_in[9];
  const float* bfc   = (const float*)d_in[10];
  const float* We    = (const float*)d_in[11];
  const float* be    = (const float*)d_in[12];
  const float* Wa    = (const float*)d_in[13];
  const float* ba    = (const float*)d_in[14];
  const float* Wk    = (const float*)d_in[15];
  const float* bk    = (const float*)d_in[16];
  const float* Wb    = (const float*)d_in[17];
  const float* bbeta = (const float*)d_in[18];

  float*    yout  = (float*)d_out;
  unsigned* flags = (unsigned*)d_ws;
  float*    r_cur = (float*)((char*)d_ws + 12288);
  float*    h_buf = (float*)((char*)d_ws + 16384);

  hipMemsetAsync(d_ws, 0, 12288, stream);   // all barrier flags = 0 every launch
  hipLaunchKernelGGL(ntm_kernel, dim3(NWG), dim3(NT), 0, stream,
                     xg, h0g, c0g, mem0g, read0g, Wih, bih, Whh, bhh,
                     Wfc, bfc, We, be, Wa, ba, Wk, bk, Wb, bbeta,
                     yout, flags, r_cur, h_buf);
}

// Round 3
// 8223.965 us; speedup vs baseline: 2.7724x; 2.1891x over previous
//
#include <hip/hip_runtime.h>
#include <math.h>

#define Bq   16
#define Tq   1024
#define INq  64
#define OUTq 64
#define Hq   512
#define Nq   128
#define Mq   40
#define SP   580      // inp row stride (floats): x[0,64) h[64,576)
#define NWGATE 128
#define NWMEM  16
#define NWOUT  8
#define NWG    152
#define NT     512
#define EPSq 1e-8f

__device__ __forceinline__ float sigmf(float x){ return 1.f/(1.f + expf(-x)); }
__device__ __forceinline__ float softplusf(float x){ return (x > 20.f) ? x : log1pf(expf(x)); }

// IC-direct (agent-scope relaxed) data movement: bypasses L1/L2, coherent at
// the Infinity Cache across XCDs. No fences anywhere -> no wbl2/buffer_inv.
__device__ __forceinline__ float2 ic_ld2(const float* p){
  unsigned long long u = __hip_atomic_load((const unsigned long long*)p,
                          __ATOMIC_RELAXED, __HIP_MEMORY_SCOPE_AGENT);
  float2 f;
  f.x = __uint_as_float((unsigned)(u & 0xffffffffull));
  f.y = __uint_as_float((unsigned)(u >> 32));
  return f;
}
__device__ __forceinline__ void ic_st1(float* p, float v){
  __hip_atomic_store((unsigned*)p, __float_as_uint(v),
                     __ATOMIC_RELAXED, __HIP_MEMORY_SCOPE_AGENT);
}

// Fence-free flag barrier. __syncthreads drains each wave's vmcnt (store acks
// from IC), so the relaxed flag store is ordered after all data stores.
__device__ __forceinline__ void gbar(unsigned* flags, unsigned target){
  __syncthreads();
  if (threadIdx.x == 0)
    __hip_atomic_store(&flags[blockIdx.x*16], target, __ATOMIC_RELAXED, __HIP_MEMORY_SCOPE_AGENT);
  if (threadIdx.x < 192){
    const int f = (threadIdx.x < NWG) ? (int)threadIdx.x : (NWG-1);
    while (__hip_atomic_load(&flags[f*16], __ATOMIC_RELAXED, __HIP_MEMORY_SCOPE_AGENT) < target) { }
  }
  __syncthreads();
}

extern "C" __global__ void __launch_bounds__(NT, 2)
ntm_kernel(const float* __restrict__ xg,  const float* __restrict__ h0g,
           const float* __restrict__ c0g, const float* __restrict__ mem0g,
           const float* __restrict__ read0g,
           const float* __restrict__ Wih, const float* __restrict__ bih,
           const float* __restrict__ Whh, const float* __restrict__ bhh,
           const float* __restrict__ Wfc, const float* __restrict__ bfc,
           const float* __restrict__ We,  const float* __restrict__ be,
           const float* __restrict__ Wa,  const float* __restrict__ ba,
           const float* __restrict__ Wk,  const float* __restrict__ bk,
           const float* __restrict__ Wb,  const float* __restrict__ bbeta,
           float* __restrict__ yout, unsigned* __restrict__ flags,
           float* __restrict__ r_cur, float* __restrict__ h_buf)
{
  const int wg  = blockIdx.x;
  const int tid = threadIdx.x;
  __shared__ __align__(16) char smem[58752];

  if (wg < NWGATE){
    // ------- gate WG: owns h-indices [wg*4, wg*4+4) => 16 gate rows -------
    float* inp_s  = (float*)smem;               // 16 x 580 floats (x | h)
    float* red_s  = (float*)(smem + 37120);     // [out*17 + kseg], 4352 floats
    float* r_s    = (float*)(smem + 54528);     // 16 x 44
    float* gate_s = (float*)(smem + 57344);     // [b*16 + l], 256
    float* c_s    = (float*)(smem + 58368);     // [hh*16 + b], 64
    float* bias_s = (float*)(smem + 58624);     // 16

    const int kseg = tid & 15;         // k-slice: 36 floats each (576 = 16*36)
    const int rg   = (tid >> 4) & 3;   // h-unit within WG; rows l = g*4+rg
    const int bg   = tid >> 6;         // batches 2*bg, 2*bg+1

    // persistent weights: 4 rows x 36 k = 36 float4, input cached in regs
    float4 w4[36];
    #pragma unroll
    for (int g = 0; g < 4; ++g){
      const int row = g*Hq + wg*4 + rg;
      #pragma unroll
      for (int kk = 0; kk < 9; ++kk){
        float v[4];
        #pragma unroll
        for (int c4 = 0; c4 < 4; ++c4){
          const int k = kseg*36 + kk*4 + c4;
          v[c4] = (k < 64) ? Wih[row*104 + k] : Whh[row*512 + (k - 64)];
        }
        w4[g*9 + kk] = make_float4(v[0], v[1], v[2], v[3]);
      }
    }
    float4 wr[10];                     // r-slice weights for finalize (tid<256)
    if (tid < 256){
      const int l = tid & 15;
      const int row = (l >> 2)*Hq + wg*4 + (l & 3);
      const float* wir = Wih + row*104 + 64;
      #pragma unroll
      for (int q = 0; q < 10; ++q) wr[q] = *(const float4*)&wir[q*4];
    }
    if (tid < 16){
      const int row = (tid >> 2)*Hq + wg*4 + (tid & 3);
      bias_s[tid] = bih[row] + bhh[row];
    }
    if (tid < 64){ const int hh = tid & 3, b = tid >> 2;
      c_s[hh*16 + b] = c0g[b*Hq + wg*4 + hh]; }
    { // stage x(0), h(-1)=h0 (h0 is pristine input: normal loads fine)
      const float4* x4 = (const float4*)xg;
      if (tid < 256){ const int b = tid >> 4, q = tid & 15;
        *(float4*)&inp_s[b*SP + q*4] = x4[(b*Tq + 0)*16 + q]; }
      const float4* h4 = (const float4*)h0g;
      #pragma unroll
      for (int j = 0; j < 4; ++j){ const int i4 = tid + 512*j;
        const int b = i4 >> 7, q = i4 & 127;
        *(float4*)&inp_s[b*SP + 64 + q*4] = h4[b*128 + q]; }
    }
    __syncthreads();

    for (int t = 0; t < Tq; ++t){
      // ---- main GEMV (x+h, k<576): overlaps the mem WGs' phase ----
      {
        float acc[4][2] = {};
        const float* base = inp_s + kseg*36;
        #pragma unroll
        for (int bl = 0; bl < 2; ++bl){
          const float* bp = base + (2*bg + bl)*SP;
          #pragma unroll
          for (int kk = 0; kk < 9; ++kk){
            const float4 f = *(const float4*)&bp[kk*4];
            #pragma unroll
            for (int g = 0; g < 4; ++g){
              acc[g][bl] += w4[g*9+kk].x*f.x + w4[g*9+kk].y*f.y
                          + w4[g*9+kk].z*f.z + w4[g*9+kk].w*f.w;
            }
          }
        }
        #pragma unroll
        for (int bl = 0; bl < 2; ++bl)
          #pragma unroll
          for (int g = 0; g < 4; ++g)
            red_s[((2*bg + bl)*16 + g*4 + rg)*17 + kseg] = acc[g][bl];
      }

      if (t > 0) gbar(flags, 2u*t);          // barB(t-1): r(t-1) @ IC
      { // stage r(t-1) via IC loads
        const float* rsrc = (t == 0) ? read0g : r_cur;
        if (tid < 320){ const int b = tid/20, mp = tid - b*20;
          const float2 rv = ic_ld2(&rsrc[b*40 + mp*2]);
          *(float2*)&r_s[b*44 + mp*2] = rv; }
      }
      __syncthreads();
      // ---- finalize: k-partial sums + bias + r-contribution ----
      if (tid < 256){
        const int l = tid & 15, fb = tid >> 4;
        float s = bias_s[l];
        const float* rp = &red_s[tid*17];
        #pragma unroll
        for (int j = 0; j < 16; ++j) s += rp[j];
        #pragma unroll
        for (int q = 0; q < 10; ++q){
          const float4 rv = *(const float4*)&r_s[fb*44 + q*4];
          s += wr[q].x*rv.x + wr[q].y*rv.y + wr[q].z*rv.z + wr[q].w*rv.w;
        }
        gate_s[fb*16 + l] = s;
      }
      __syncthreads();
      if (tid < 64){
        const int hh = tid & 3, b = tid >> 2;
        const float gi = gate_s[b*16 + hh];
        const float gf = gate_s[b*16 + 4 + hh];
        const float gc = gate_s[b*16 + 8 + hh];
        const float go = gate_s[b*16 + 12 + hh];
        const float iv = sigmf(gi), fv = sigmf(gf), gv = tanhf(gc), ov = sigmf(go);
        const float cn = fv*c_s[hh*16 + b] + iv*gv;
        const float hn = ov*tanhf(cn);
        c_s[hh*16 + b] = cn;
        ic_st1(&h_buf[(t & 1)*(Bq*Hq) + b*Hq + wg*4 + hh], hn);
        if (t == Tq - 1){
          yout[Bq*Tq*OUTq + b*Hq + wg*4 + hh] = hn;                // final h
          yout[Bq*Tq*OUTq + Bq*Hq + b*Hq + wg*4 + hh] = cn;        // final c
        }
      }
      gbar(flags, 2u*t + 1u);                // barA(t): h(t) @ IC
      if (t + 1 < Tq){                       // stage h(t), x(t+1) for next GEMV
        const float* hsrc = h_buf + (t & 1)*(Bq*Hq);
        #pragma unroll
        for (int j = 0; j < 8; ++j){
          const int i = tid + 512*j;         // 4096 ull total
          const int b = i >> 8, q = i & 255;
          const float2 hv = ic_ld2(&hsrc[b*512 + q*2]);
          *(float2*)&inp_s[b*SP + 64 + q*2] = hv;
        }
        const float4* x4 = (const float4*)xg;
        if (tid < 256){ const int b = tid >> 4, q = tid & 15;
          *(float4*)&inp_s[b*SP + q*4] = x4[(b*Tq + (t + 1))*16 + q]; }
      }
      __syncthreads();
    }
    // final arrive at barB(1023) so mem/out WGs can exit
    __syncthreads();
    if (tid == 0)
      __hip_atomic_store(&flags[wg*16], 2u*Tq, __ATOMIC_RELAXED, __HIP_MEMORY_SCOPE_AGENT);
  }
  else if (wg < NWGATE + NWMEM){
    // ---------------- memory workgroup: owns batch b ----------------
    const int bat = wg - NWGATE;
    float* mem_s  = (float*)smem;               // 128 x 41
    float* h_s    = (float*)(smem + 20992);     // 512
    float* key_s  = (float*)(smem + 23040);     // 40
    float* e_s    = (float*)(smem + 23200);     // 40
    float* a_s    = (float*)(smem + 23360);     // 40
    float* hred_s = (float*)(smem + 23520);     // 128*4
    float* w_s    = (float*)(smem + 25568);     // 128
    float* sc_s   = (float*)(smem + 26080);     // 128
    float* rred_s = (float*)(smem + 26592);     // 40*8
    float* scal_s = (float*)(smem + 27872);     // 8

    #pragma unroll
    for (int j = 0; j < 10; ++j){
      const int e = j*512 + tid;
      const int n = e / 40, m = e - n*40;
      mem_s[n*41 + m] = mem0g[bat*(Nq*Mq) + e];
    }
    const int o  = tid & 127;
    const int kc = tid >> 7;
    const float* wrow = nullptr; float hbias = 0.f;
    if      (o < 40){  wrow = Wk + o*Hq;        hbias = bk[o]; }
    else if (o < 80){  wrow = We + (o-40)*Hq;   hbias = be[o-40]; }
    else if (o < 120){ wrow = Wa + (o-80)*Hq;   hbias = ba[o-80]; }
    else if (o == 120){ wrow = Wb;              hbias = bbeta[0]; }
    float4 wv[32];
    if (wrow){
      const float4* wp = (const float4*)(wrow + kc*128);
      #pragma unroll
      for (int kk = 0; kk < 32; ++kk) wv[kk] = wp[kk];
    } else {
      #pragma unroll
      for (int kk = 0; kk < 32; ++kk) wv[kk] = make_float4(0.f,0.f,0.f,0.f);
    }

    for (int t = 0; t < Tq; ++t){
      gbar(flags, 2u*t + 1u);               // barA(t): h(t) @ IC
      if (tid < 256){
        const float2 hv = ic_ld2(&h_buf[(t & 1)*(Bq*Hq) + bat*Hq + tid*2]);
        *(float2*)&h_s[tid*2] = hv;
      }
      __syncthreads();
      { // heads GEMV: 121 outputs x 512 (h_s reads wave-uniform -> broadcast)
        float p = 0.f;
        #pragma unroll
        for (int kk = 0; kk < 32; ++kk){
          const float4 hv = *(const float4*)&h_s[kc*128 + kk*4];
          p += wv[kk].x*hv.x + wv[kk].y*hv.y + wv[kk].z*hv.z + wv[kk].w*hv.w;
        }
        hred_s[o*4 + kc] = p;
      }
      __syncthreads();
      if (tid < 128){
        const float s = hred_s[tid*4] + hred_s[tid*4+1] + hred_s[tid*4+2] + hred_s[tid*4+3] + hbias;
        if      (tid < 40)  key_s[tid]     = tanhf(s);
        else if (tid < 80)  e_s[tid-40]    = sigmf(s);
        else if (tid < 120) a_s[tid-80]    = tanhf(s);
        else if (tid == 120) scal_s[1]     = softplusf(s) + EPSq;  // beta
      }
      __syncthreads();
      if (tid < 64){
        float v = (tid < 40) ? key_s[tid]*key_s[tid] : 0.f;
        #pragma unroll
        for (int off = 32; off; off >>= 1) v += __shfl_xor(v, off);
        if (tid == 0) scal_s[0] = 1.f/(sqrtf(v) + EPSq);           // 1/(||key||+eps)
      }
      __syncthreads();
      if (tid < 128){
        const int n = tid;
        float q = 0.f, d = 0.f;
        #pragma unroll
        for (int m = 0; m < 40; ++m){
          const float mv = mem_s[n*41 + m];
          q += mv*mv; d += mv*key_s[m];
        }
        const float sim = d * scal_s[0] / (sqrtf(q) + EPSq);
        sc_s[n] = scal_s[1] * sim;
      }
      __syncthreads();
      if (tid < 64){
        float v = fmaxf(sc_s[tid], sc_s[tid + 64]);
        #pragma unroll
        for (int off = 32; off; off >>= 1) v = fmaxf(v, __shfl_xor(v, off));
        if (tid == 0) scal_s[2] = v;
      }
      __syncthreads();
      if (tid < 128) w_s[tid] = expf(sc_s[tid] - scal_s[2]);
      __syncthreads();
      if (tid < 64){
        float v = w_s[tid] + w_s[tid + 64];
        #pragma unroll
        for (int off = 32; off; off >>= 1) v += __shfl_xor(v, off);
        if (tid == 0) scal_s[3] = 1.f/v;
      }
      __syncthreads();
      if (tid < 128) w_s[tid] *= scal_s[3];
      __syncthreads();
      { // erase/add write
        const int n = tid & 127, mg = tid >> 7;
        const float wn = w_s[n];
        #pragma unroll
        for (int mm = 0; mm < 10; ++mm){
          const int m = mg*10 + mm, idx = n*41 + m;
          const float mv = mem_s[idx];
          mem_s[idx] = mv*(1.f - wn*e_s[m]) + wn*a_s[m];
        }
      }
      __syncthreads();
      if (tid < 320){ // read vector partials
        const int m = tid % 40, ng = tid / 40;
        float p = 0.f;
        #pragma unroll
        for (int j = 0; j < 16; ++j){
          const int n = ng*16 + j;
          p += w_s[n]*mem_s[n*41 + m];
        }
        rred_s[m*8 + ng] = p;
      }
      __syncthreads();
      if (tid < 40){
        float rsum = 0.f;
        #pragma unroll
        for (int j = 0; j < 8; ++j) rsum += rred_s[tid*8 + j];
        ic_st1(&r_cur[bat*Mq + tid], rsum);
      }
      gbar(flags, 2u*t + 2u);               // barB(t): r(t) @ IC
    }
  }
  else {
    // ---------------- out workgroup: owns 8 output columns ----------------
    const int oo = wg - (NWGATE + NWMEM);
    float* wfc_s  = (float*)smem;               // 8 x 516
    float* hall_s = (float*)(smem + 16512);     // 16 x 516
    float* ored_s = (float*)(smem + 49536);     // 128*4
    float* bfc_s  = (float*)(smem + 51584);     // 8
    {
      const float4* wp = (const float4*)Wfc;
      #pragma unroll
      for (int j = 0; j < 2; ++j){
        const int i4 = j*512 + tid;
        const int col = i4 >> 7, q = i4 & 127;
        *(float4*)&wfc_s[col*516 + q*4] = wp[(oo*8 + col)*128 + q];
      }
      if (tid < 8) bfc_s[tid] = bfc[oo*8 + tid];
    }
    for (int t = 0; t < Tq; ++t){
      gbar(flags, 2u*t + 1u);               // A
      gbar(flags, 2u*t + 2u);               // B
      // compute out(t) hidden behind next gate/mem phase (parity valid 1 extra step)
      const float* hsrc = h_buf + (t & 1)*(Bq*Hq);
      #pragma unroll
      for (int j = 0; j < 8; ++j){
        const int i = tid + 512*j;
        const int b = i >> 8, q = i & 255;
        const float2 hv = ic_ld2(&hsrc[b*512 + q*2]);
        *(float2*)&hall_s[b*516 + q*2] = hv;
      }
      __syncthreads();
      {
        const int col = tid & 7, b = (tid >> 3) & 15, kc = tid >> 7;
        float p = 0.f;
        #pragma unroll
        for (int kk = 0; kk < 32; ++kk){
          const int k = kc*128 + kk*4;
          const float4 wvv = *(const float4*)&wfc_s[col*516 + k];
          const float4 hvv = *(const float4*)&hall_s[b*516 + k];
          p += wvv.x*hvv.x + wvv.y*hvv.y + wvv.z*hvv.z + wvv.w*hvv.w;
        }
        ored_s[(b*8 + col)*4 + kc] = p;
      }
      __syncthreads();
      if (tid < 128){
        const int b = tid >> 3, col = tid & 7;
        const float* op = &ored_s[(b*8 + col)*4];
        const float s = op[0] + op[1] + op[2] + op[3] + bfc_s[col];
        yout[(b*Tq + t)*OUTq + oo*8 + col] = tanhf(s);
      }
      __syncthreads();
    }
  }
}

extern "C" void kernel_launch(void* const* d_in, const int* in_sizes, int n_in,
                              void* d_out, int out_size, void* d_ws, size_t ws_size,
                              hipStream_t stream){
  const float* xg    = (const float*)d_in[0];
  const float* h0g   = (const float*)d_in[1];
  const float* c0g   = (const float*)d_in[2];
  const float* mem0g = (const float*)d_in[3];
  const float* read0g= (const float*)d_in[4];
  const float* Wih   = (const float*)d_in[5];
  const float* bih   = (const float*)d_in[6];
  const float* Whh   = (const float*)d_in[7];
  const float* bhh   = (const float*)d_in[8];
  const float* Wfc   = (const float*)d_in[9];
  const float* bfc   = (const float*)d_in[10];
  const float* We    = (const float*)d_in[11];
  const float* be    = (const float*)d_in[12];
  const float* Wa    = (const float*)d_in[13];
  const float* ba    = (const float*)d_in[14];
  const float* Wk    = (const float*)d_in[15];
  const float* bk    = (const float*)d_in[16];
  const float* Wb    = (const float*)d_in[17];
  const float* bbeta = (const float*)d_in[18];

  float*    yout  = (float*)d_out;
  unsigned* flags = (unsigned*)d_ws;
  float*    r_cur = (float*)((char*)d_ws + 12288);
  float*    h_buf = (float*)((char*)d_ws + 16384);

  hipMemsetAsync(d_ws, 0, 16384, stream);   // flags + r_cur cleared every launch
  hipLaunchKernelGGL(ntm_kernel, dim3(NWG), dim3(NT), 0, stream,
                     xg, h0g, c0g, mem0g, read0g, Wih, bih, Whh, bhh,
                     Wfc, bfc, We, be, Wa, ba, Wk, bk, Wb, bbeta,
                     yout, flags, r_cur, h_buf);
}